// Round 8
// baseline (418.714 us; speedup 1.0000x reference)
//
#include <hip/hip_runtime.h>

#define B_ 8
#define T_ 4096
#define D_ 768
#define NH_ 12
#define M_ 64
#define ALPHA_ 0.1f

#define CCH 16         // chunks over T
#define CHUNK_T 256    // t per block

using half8 = __attribute__((ext_vector_type(8))) _Float16;
using short8 = __attribute__((ext_vector_type(8))) short;
using f32x4 = __attribute__((ext_vector_type(4))) float;

__device__ __forceinline__ unsigned int f2h2(float a, float b) {
    unsigned short ua = __builtin_bit_cast(unsigned short, (_Float16)a);
    unsigned short ub = __builtin_bit_cast(unsigned short, (_Float16)b);
    return (unsigned int)ua | ((unsigned int)ub << 16);
}
__device__ __forceinline__ float h2f(unsigned short u) {
    return (float)__builtin_bit_cast(_Float16, u);
}
// async global->LDS, 16 B per lane; LDS dst = wave-uniform base + lane*16
__device__ __forceinline__ void gload_lds16(const void* g, void* l) {
    __builtin_amdgcn_global_load_lds(
        (const __attribute__((address_space(1))) unsigned int*)g,
        (__attribute__((address_space(3))) unsigned int*)l, 16, 0, 0);
}

// ---------------------------------------------------------------------------
// kprep: heterogeneous. Blocks [0,6144): H fp32 -> fp16. Blocks [6144,6216):
// P16[h,m,e] = (1/8)*sum_i proto[m,h*64+i]*W[h*64+i,e]; block 6144 also
// zeroes the 96 combine counters (ws is re-poisoned 0xAA before every call).
// ---------------------------------------------------------------------------
__global__ __launch_bounds__(256) void kprep(const float* __restrict__ H,
                                             const float* __restrict__ proto,
                                             const float* __restrict__ W,
                                             unsigned short* __restrict__ H16,
                                             unsigned short* __restrict__ P16,
                                             unsigned int* __restrict__ counters) {
    const int tid = threadIdx.x;
    __shared__ __align__(16) float Ws[64 * 128];
    __shared__ __align__(16) float Ks[64 * 64];

    if (blockIdx.x < 6144) {
        const int i = blockIdx.x * 256 + tid;
#pragma unroll
        for (int j = 0; j < 4; ++j) {
            const int idx = i + j * 1572864;
            const float4 v = reinterpret_cast<const float4*>(H)[idx];
            uint2 pk = {f2h2(v.x, v.y), f2h2(v.z, v.w)};
            reinterpret_cast<uint2*>(H16)[idx] = pk;
        }
        return;
    }
    const int r  = blockIdx.x - 6144;
    if (r == 0 && tid < 96) counters[tid] = 0u;
    const int et = r % 6;
    const int h  = r / 6;

#pragma unroll
    for (int j = 0; j < 8; ++j) {
        int f = tid + j * 256;
        int i = f >> 5, c4 = f & 31;
        const float4 v = *reinterpret_cast<const float4*>(
            W + (size_t)(h * 64 + i) * D_ + et * 128 + c4 * 4);
        *reinterpret_cast<float4*>(&Ws[i * 128 + c4 * 4]) = v;
    }
#pragma unroll
    for (int j = 0; j < 4; ++j) {
        int f = tid + j * 256;
        int m = f >> 4, i4 = f & 15;
        const float4 v = *reinterpret_cast<const float4*>(
            proto + (size_t)m * D_ + h * 64 + i4 * 4);
        Ks[(i4 * 4 + 0) * 64 + m] = v.x;
        Ks[(i4 * 4 + 1) * 64 + m] = v.y;
        Ks[(i4 * 4 + 2) * 64 + m] = v.z;
        Ks[(i4 * 4 + 3) * 64 + m] = v.w;
    }
    __syncthreads();

    const int m0 = (tid >> 5) * 8;
    const int e0 = (tid & 31) * 4;
    float acc[8][4];
#pragma unroll
    for (int i = 0; i < 8; ++i)
#pragma unroll
        for (int j = 0; j < 4; ++j) acc[i][j] = 0.f;

    for (int i = 0; i < 64; ++i) {
        const float4 bb = *reinterpret_cast<const float4*>(&Ws[i * 128 + e0]);
        const float4 a0 = *reinterpret_cast<const float4*>(&Ks[i * 64 + m0]);
        const float4 a1 = *reinterpret_cast<const float4*>(&Ks[i * 64 + m0 + 4]);
        const float a[8] = {a0.x, a0.y, a0.z, a0.w, a1.x, a1.y, a1.z, a1.w};
#pragma unroll
        for (int mi = 0; mi < 8; ++mi) {
            acc[mi][0] = fmaf(a[mi], bb.x, acc[mi][0]);
            acc[mi][1] = fmaf(a[mi], bb.y, acc[mi][1]);
            acc[mi][2] = fmaf(a[mi], bb.z, acc[mi][2]);
            acc[mi][3] = fmaf(a[mi], bb.w, acc[mi][3]);
        }
    }
#pragma unroll
    for (int mi = 0; mi < 8; ++mi) {
        size_t idx = (size_t)(h * 64 + m0 + mi) * D_ + et * 128 + e0;
        uint2 pk = {f2h2(acc[mi][0] * 0.125f, acc[mi][1] * 0.125f),
                    f2h2(acc[mi][2] * 0.125f, acc[mi][3] * 0.125f)};
        *reinterpret_cast<uint2*>(P16 + idx) = pk;
    }
}

// ---------------------------------------------------------------------------
// Kernel 1: r5's verified body (score MFMA via global_load_lds w=16 +
// XOR-swizzle, register softmax, segmented suffix scan, fp16 MFMA partial)
// + last-block combine: 16th finisher per (b,h) applies cross-chunk suffix
// products + s0 and writes out (device-scope atomics + threadfence).
// grid 1536 (b = p&7 pins batch per XCD), 256 threads, dyn LDS 51712 B.
//
// LDS (bytes): [0,32768) A fp16[256t][64k] swz | [32768,40960) B[64m][64k]
//   alias: [0,33792) wT fp16[64m][264t] | [33792,50688) Hh fp16[32d][264t]
//   [50688,51712) segprod f32[64][4]
// ---------------------------------------------------------------------------
#define LDS_BYTES 51712

__global__ __launch_bounds__(256, 3) void k1(const unsigned short* __restrict__ H16,
                                             const unsigned short* __restrict__ P16,
                                             const float* __restrict__ s0,
                                             float* __restrict__ chunkprod,
                                             float* __restrict__ partial,
                                             unsigned int* __restrict__ counters,
                                             float* __restrict__ out) {
    const int p = blockIdx.x;
    const int b = p & 7;
    const int s = p >> 3;
    const int h = s % 12;
    const int c = s / 12;
    const int tid = threadIdx.x;
    const int wv  = tid >> 6;
    const int lane = tid & 63;
    const int l15 = lane & 15;
    const int q4  = lane >> 4;

    extern __shared__ __align__(16) unsigned char smem[];
    unsigned short* wT = (unsigned short*)(smem);
    unsigned short* Hh = (unsigned short*)(smem + 33792);
    float* segprod = (float*)(smem + 50688);
    __shared__ int isLast;

    const size_t Hrow = (size_t)(b * T_ + c * CHUNK_T);
    const unsigned short* gA = H16 + Hrow * D_;
    const unsigned short* gB = P16 + (size_t)h * 64 * D_;

    // ======== score GEMM: 256t x 64m, K=768, fp16, DMA-staged ========
    f32x4 acc[4][4] = {};   // t = tt*16+q4*4+rg, m = mt*16+l15; wave owns t[wv*64,+64)

    for (int kt = 0; kt < 12; ++kt) {
        __syncthreads();
#pragma unroll
        for (int j = 0; j < 8; ++j) {
            int sl = j * 256 + tid;
            int rr = sl >> 3, gp = sl & 7, g = gp ^ (rr & 7);
            gload_lds16(gA + (size_t)rr * D_ + kt * 64 + g * 8, smem + sl * 16);
        }
#pragma unroll
        for (int j = 0; j < 2; ++j) {
            int sl = j * 256 + tid;
            int rr = sl >> 3, gp = sl & 7, g = gp ^ (rr & 7);
            gload_lds16(gB + (size_t)rr * D_ + kt * 64 + g * 8, smem + 32768 + sl * 16);
        }
        __syncthreads();
#pragma unroll
        for (int ks = 0; ks < 2; ++ks) {
            const int gp = ((ks * 4 + q4) ^ (l15 & 7)) * 16;
            half8 af[4], bf[4];
#pragma unroll
            for (int tt = 0; tt < 4; ++tt)
                af[tt] = *reinterpret_cast<const half8*>(
                    smem + (wv * 64 + tt * 16 + l15) * 128 + gp);
#pragma unroll
            for (int mt = 0; mt < 4; ++mt)
                bf[mt] = *reinterpret_cast<const half8*>(
                    smem + 32768 + (mt * 16 + l15) * 128 + gp);
#pragma unroll
            for (int tt = 0; tt < 4; ++tt)
#pragma unroll
                for (int mt = 0; mt < 4; ++mt)
                    acc[tt][mt] = __builtin_amdgcn_mfma_f32_16x16x32_f16(
                        af[tt], bf[mt], acc[tt][mt], 0, 0, 0);
        }
    }
    __syncthreads();   // frag reads done; wT aliases A/B

    // ======== softmax over m in registers ========
#pragma unroll
    for (int tt = 0; tt < 4; ++tt)
#pragma unroll
        for (int rg = 0; rg < 4; ++rg) {
            float mx = fmaxf(fmaxf(acc[tt][0][rg], acc[tt][1][rg]),
                             fmaxf(acc[tt][2][rg], acc[tt][3][rg]));
#pragma unroll
            for (int msk = 1; msk <= 8; msk <<= 1)
                mx = fmaxf(mx, __shfl_xor(mx, msk, 64));
            float e0 = __expf(acc[tt][0][rg] - mx);
            float e1 = __expf(acc[tt][1][rg] - mx);
            float e2 = __expf(acc[tt][2][rg] - mx);
            float e3 = __expf(acc[tt][3][rg] - mx);
            float sm = (e0 + e1) + (e2 + e3);
#pragma unroll
            for (int msk = 1; msk <= 8; msk <<= 1)
                sm += __shfl_xor(sm, msk, 64);
            float inv = 1.0f / sm;
            acc[tt][0][rg] = e0 * inv;
            acc[tt][1][rg] = e1 * inv;
            acc[tt][2][rg] = e2 * inv;
            acc[tt][3][rg] = e3 * inv;
        }
    // pack w -> wT[m][t] fp16, pitch 264
#pragma unroll
    for (int tt = 0; tt < 4; ++tt)
#pragma unroll
        for (int mt = 0; mt < 4; ++mt) {
            uint2 pk = {f2h2(acc[tt][mt][0], acc[tt][mt][1]),
                        f2h2(acc[tt][mt][2], acc[tt][mt][3])};
            *reinterpret_cast<uint2*>(
                wT + (mt * 16 + l15) * 264 + wv * 64 + tt * 16 + q4 * 4) = pk;
        }
    __syncthreads();

    // ======== segmented suffix gate scan (4 segments x 64 t) ========
    {
        const int g = tid >> 6, m_s = tid & 63;
        unsigned short* rowp = wT + m_s * 264 + g * 64;
        float pband = 1.0f;
#pragma unroll
        for (int oct = 0; oct < 8; ++oct) {
            short8 v = *reinterpret_cast<const short8*>(rowp + oct * 8);
#pragma unroll
            for (int j = 0; j < 8; ++j)
                pband *= fmaf(-ALPHA_, h2f((unsigned short)v[j]), 1.0f);
        }
        segprod[m_s * 4 + g] = pband;
        __syncthreads();
        float R = 1.0f;
#pragma unroll
        for (int gg = 1; gg < 4; ++gg)
            if (g + gg < 4) R *= segprod[m_s * 4 + g + gg];
#pragma unroll
        for (int oct = 7; oct >= 0; --oct) {
            short8 v = *reinterpret_cast<const short8*>(rowp + oct * 8);
            short8 o;
#pragma unroll
            for (int j = 7; j >= 0; --j) {
                float w = h2f((unsigned short)v[j]);
                _Float16 we = (_Float16)(ALPHA_ * w * R);
                o[j] = (short)__builtin_bit_cast(unsigned short, we);
                R *= fmaf(-ALPHA_, w, 1.0f);
            }
            *reinterpret_cast<short8*>(rowp + oct * 8) = o;
        }
    }
    __syncthreads();   // w_eff visible

    // ======== partial GEMM: pacc[m][d] += w_eff^T . H_head (fp16) ========
    f32x4 pacc[4] = {};   // wave owns m[wv*16,+16), 4 d-tiles of 16
    for (int hf = 0; hf < 2; ++hf) {
        if (hf) __syncthreads();
        {
            const int dp = tid & 15, tg = tid >> 4;
            const unsigned short* src = H16 + (Hrow + tg * 16) * D_
                                        + h * 64 + hf * 32 + 2 * dp;
            unsigned short* dst0 = Hh + (2 * dp) * 264 + tg * 16;
            unsigned short* dst1 = Hh + (2 * dp + 1) * 264 + tg * 16;
#pragma unroll
            for (int i = 0; i < 16; ++i) {
                unsigned int v = *reinterpret_cast<const unsigned int*>(src + (size_t)i * D_);
                dst0[i] = (unsigned short)(v & 0xffffu);
                dst1[i] = (unsigned short)(v >> 16);
            }
        }
        __syncthreads();
#pragma unroll
        for (int ks = 0; ks < 8; ++ks) {
            half8 a = *reinterpret_cast<const half8*>(
                wT + (wv * 16 + l15) * 264 + ks * 32 + q4 * 8);
#pragma unroll
            for (int dt = 0; dt < 2; ++dt) {
                half8 bb = *reinterpret_cast<const half8*>(
                    Hh + (dt * 16 + l15) * 264 + ks * 32 + q4 * 8);
                pacc[hf * 2 + dt] = __builtin_amdgcn_mfma_f32_16x16x32_f16(
                    a, bb, pacc[hf * 2 + dt], 0, 0, 0);
            }
        }
    }

    // ======== publish chunk results ========
    const int bh = b * NH_ + h;
    const int chunkIdx = bh * CCH + c;
    if (tid < 64)
        chunkprod[(size_t)chunkIdx * 64 + tid] =
            (segprod[tid * 4 + 0] * segprod[tid * 4 + 1]) *
            (segprod[tid * 4 + 2] * segprod[tid * 4 + 3]);
#pragma unroll
    for (int dt = 0; dt < 4; ++dt)
#pragma unroll
        for (int rg = 0; rg < 4; ++rg)
            partial[((size_t)chunkIdx * 64 + wv * 16 + q4 * 4 + rg) * 64 + dt * 16 + l15] =
                pacc[dt][rg];

    // ======== last-block combine for this (b,h) ========
    __threadfence();   // make chunkprod/partial visible device-wide
    if (tid == 0)
        isLast = (atomicAdd(&counters[bh], 1u) == CCH - 1) ? 1 : 0;
    __syncthreads();
    if (isLast) {
        __threadfence();   // acquire: see other blocks' writes
        const size_t cpBase = (size_t)bh * CCH;
        const int m  = tid >> 2;
        const int d0 = (tid & 3) * 16;
        float sfx[CCH];
        float run = 1.0f;
#pragma unroll
        for (int c2 = CCH - 1; c2 >= 0; --c2) {
            sfx[c2] = run;
            run *= chunkprod[(cpBase + c2) * M_ + m];
        }
        float4 acc4[4];
#pragma unroll
        for (int qq = 0; qq < 4; ++qq) {
            const float4 v = *reinterpret_cast<const float4*>(
                s0 + (size_t)m * D_ + h * 64 + d0 + qq * 4);
            acc4[qq] = make_float4(v.x * run, v.y * run, v.z * run, v.w * run);
        }
        for (int c2 = 0; c2 < CCH; ++c2) {
            const float sv = sfx[c2];
            const size_t base = ((cpBase + c2) * M_ + m) * 64 + d0;
#pragma unroll
            for (int qq = 0; qq < 4; ++qq) {
                const float4 pp = *reinterpret_cast<const float4*>(partial + base + qq * 4);
                acc4[qq].x = fmaf(sv, pp.x, acc4[qq].x);
                acc4[qq].y = fmaf(sv, pp.y, acc4[qq].y);
                acc4[qq].z = fmaf(sv, pp.z, acc4[qq].z);
                acc4[qq].w = fmaf(sv, pp.w, acc4[qq].w);
            }
        }
        const size_t ob = (size_t)(b * M_ + m) * D_ + h * 64 + d0;
#pragma unroll
        for (int qq = 0; qq < 4; ++qq)
            *reinterpret_cast<float4*>(out + ob + qq * 4) = acc4[qq];
    }
}

// ---------------------------------------------------------------------------
extern "C" void kernel_launch(void* const* d_in, const int* in_sizes, int n_in,
                              void* d_out, int out_size, void* d_ws, size_t ws_size,
                              hipStream_t stream) {
    const float* H     = (const float*)d_in[0];
    const float* proto = (const float*)d_in[1];
    const float* W     = (const float*)d_in[2];
    const float* s0    = (const float*)d_in[3];
    float* out = (float*)d_out;

    // ws: H16 u16[25165824] (50.3 MB) | P16 u16[589824] (1.18 MB)
    //     | chunkprod f32[98304] | partial f32[6291456] (25.2 MB)
    //     | counters u32[96]                                    ~77.1 MB
    unsigned short* H16 = (unsigned short*)d_ws;
    unsigned short* P16 = (unsigned short*)((unsigned char*)d_ws + 50331648);
    float* chunkprod = (float*)((unsigned char*)d_ws + 51511296);
    float* partial   = (float*)((unsigned char*)d_ws + 51904512);
    unsigned int* counters = (unsigned int*)((unsigned char*)d_ws + 77070336);

    kprep<<<dim3(6216), 256, 0, stream>>>(H, proto, W, H16, P16, counters);
    k1<<<dim3(1536), 256, LDS_BYTES, stream>>>(H16, P16, s0, chunkprod, partial,
                                               counters, out);
}

// Round 9
// 374.002 us; speedup vs baseline: 1.1195x; 1.1195x over previous
//
#include <hip/hip_runtime.h>

#define B_ 8
#define T_ 4096
#define D_ 768
#define NH_ 12
#define M_ 64
#define ALPHA_ 0.1f

#define CCH 16         // chunks over T
#define CHUNK_T 256    // t per block

using half8 = __attribute__((ext_vector_type(8))) _Float16;
using short8 = __attribute__((ext_vector_type(8))) short;
using f32x4 = __attribute__((ext_vector_type(4))) float;

__device__ __forceinline__ unsigned int f2h2(float a, float b) {
    unsigned short ua = __builtin_bit_cast(unsigned short, (_Float16)a);
    unsigned short ub = __builtin_bit_cast(unsigned short, (_Float16)b);
    return (unsigned int)ua | ((unsigned int)ub << 16);
}
__device__ __forceinline__ float h2f(unsigned short u) {
    return (float)__builtin_bit_cast(_Float16, u);
}
__device__ __forceinline__ half8 cvt8(float4 a, float4 b) {
    half8 r;
    r[0] = (_Float16)a.x; r[1] = (_Float16)a.y;
    r[2] = (_Float16)a.z; r[3] = (_Float16)a.w;
    r[4] = (_Float16)b.x; r[5] = (_Float16)b.y;
    r[6] = (_Float16)b.z; r[7] = (_Float16)b.w;
    return r;
}
// async global->LDS, 16 B per lane; LDS dst = wave-uniform base + lane*16
__device__ __forceinline__ void gload_lds16(const void* g, void* l) {
    __builtin_amdgcn_global_load_lds(
        (const __attribute__((address_space(1))) unsigned int*)g,
        (__attribute__((address_space(3))) unsigned int*)l, 16, 0, 0);
}

// ---------------------------------------------------------------------------
// kP: P16[h,m,e] = (1/8) * sum_i proto[m, h*64+i] * W[h*64+i, e] -> fp16.
// grid (6 e-tiles of 128, 12 heads), 256 threads.  (r5-verified)
// ---------------------------------------------------------------------------
__global__ __launch_bounds__(256) void kP(const float* __restrict__ proto,
                                          const float* __restrict__ W,
                                          unsigned short* __restrict__ P16) {
    const int et = blockIdx.x;
    const int h  = blockIdx.y;
    const int tid = threadIdx.x;

    __shared__ __align__(16) float Ws[64 * 128];
    __shared__ __align__(16) float Ks[64 * 64];

#pragma unroll
    for (int j = 0; j < 8; ++j) {
        int f = tid + j * 256;
        int i = f >> 5, c4 = f & 31;
        const float4 v = *reinterpret_cast<const float4*>(
            W + (size_t)(h * 64 + i) * D_ + et * 128 + c4 * 4);
        *reinterpret_cast<float4*>(&Ws[i * 128 + c4 * 4]) = v;
    }
#pragma unroll
    for (int j = 0; j < 4; ++j) {
        int f = tid + j * 256;
        int m = f >> 4, i4 = f & 15;
        const float4 v = *reinterpret_cast<const float4*>(
            proto + (size_t)m * D_ + h * 64 + i4 * 4);
        Ks[(i4 * 4 + 0) * 64 + m] = v.x;
        Ks[(i4 * 4 + 1) * 64 + m] = v.y;
        Ks[(i4 * 4 + 2) * 64 + m] = v.z;
        Ks[(i4 * 4 + 3) * 64 + m] = v.w;
    }
    __syncthreads();

    const int m0 = (tid >> 5) * 8;
    const int e0 = (tid & 31) * 4;
    float acc[8][4];
#pragma unroll
    for (int i = 0; i < 8; ++i)
#pragma unroll
        for (int j = 0; j < 4; ++j) acc[i][j] = 0.f;

    for (int i = 0; i < 64; ++i) {
        const float4 bb = *reinterpret_cast<const float4*>(&Ws[i * 128 + e0]);
        const float4 a0 = *reinterpret_cast<const float4*>(&Ks[i * 64 + m0]);
        const float4 a1 = *reinterpret_cast<const float4*>(&Ks[i * 64 + m0 + 4]);
        const float a[8] = {a0.x, a0.y, a0.z, a0.w, a1.x, a1.y, a1.z, a1.w};
#pragma unroll
        for (int mi = 0; mi < 8; ++mi) {
            acc[mi][0] = fmaf(a[mi], bb.x, acc[mi][0]);
            acc[mi][1] = fmaf(a[mi], bb.y, acc[mi][1]);
            acc[mi][2] = fmaf(a[mi], bb.z, acc[mi][2]);
            acc[mi][3] = fmaf(a[mi], bb.w, acc[mi][3]);
        }
    }
#pragma unroll
    for (int mi = 0; mi < 8; ++mi) {
        size_t idx = (size_t)(h * 64 + m0 + mi) * D_ + et * 128 + e0;
        uint2 pk = {f2h2(acc[mi][0] * 0.125f, acc[mi][1] * 0.125f),
                    f2h2(acc[mi][2] * 0.125f, acc[mi][3] * 0.125f)};
        *reinterpret_cast<uint2*>(P16 + idx) = pk;
    }
}

// ---------------------------------------------------------------------------
// Kernel 1: per (chunk=256t, head, batch). Score GEMM stages A as RAW FP32
// from H via global_load_lds w=16 (K-tile 32: A 32 KB fp32 + B 4 KB fp16),
// granule-major LDS layout (slot = g*256 + r) -> DMA lane-linear AND frag
// ds_read 2-way-max banks, no swizzle. fp32->fp16 cvt at frag read.
// Then register softmax + segmented suffix scan + fp16 MFMA partial (r5).
// grid 1536 (b = p&7 pins batch per XCD), 256 threads, dyn LDS 51712 B.
//
// LDS (bytes): [0,32768) A f32 granule-major | [32768,36864) B fp16 gran-major
//   alias: [0,33792) wT fp16[64m][264t] | [33792,50688) Hh fp16[32d][264t]
//   [50688,51712) segprod f32[64][4]
// ---------------------------------------------------------------------------
#define LDS_BYTES 51712

__global__ __launch_bounds__(256, 3) void k1(const float* __restrict__ H,
                                             const unsigned short* __restrict__ P16,
                                             float* __restrict__ chunkprod,
                                             float* __restrict__ partial) {
    const int p = blockIdx.x;
    const int b = p & 7;
    const int s = p >> 3;
    const int h = s % 12;
    const int c = s / 12;
    const int tid = threadIdx.x;
    const int wv  = tid >> 6;
    const int lane = tid & 63;
    const int l15 = lane & 15;
    const int q4  = lane >> 4;

    extern __shared__ __align__(16) unsigned char smem[];
    unsigned short* wT = (unsigned short*)(smem);
    unsigned short* Hh = (unsigned short*)(smem + 33792);
    float* segprod = (float*)(smem + 50688);

    const size_t Hrow = (size_t)(b * T_ + c * CHUNK_T);
    const float* gA = H + Hrow * D_;
    const unsigned short* gB = P16 + (size_t)h * 64 * D_;

    // ======== score GEMM: 256t x 64m, K=768 (24 x 32-K tiles) ========
    f32x4 acc[4][4] = {};   // t = tt*16+q4*4+rg, m = mt*16+l15; wave owns t[wv*64,+64)

    for (int kt = 0; kt < 24; ++kt) {
        __syncthreads();
        // A: 2048 granules (16 B = 4 floats); slot sl = g*256 + r; lane: r=tid, g=j
#pragma unroll
        for (int j = 0; j < 8; ++j)
            gload_lds16(gA + (size_t)tid * D_ + kt * 32 + j * 4,
                        smem + (j * 256 + tid) * 16);
        // B: 256 granules (16 B = 8 halfs); r = tid&63, g = tid>>6
        gload_lds16(gB + (size_t)(tid & 63) * D_ + kt * 32 + (tid >> 6) * 8,
                    smem + 32768 + tid * 16);
        __syncthreads();

        half8 af[4], bf[4];
#pragma unroll
        for (int tt = 0; tt < 4; ++tt) {
            const int row = wv * 64 + tt * 16 + l15;
            const float4 lo = *reinterpret_cast<const float4*>(
                smem + ((2 * q4) * 256 + row) * 16);
            const float4 hi = *reinterpret_cast<const float4*>(
                smem + ((2 * q4 + 1) * 256 + row) * 16);
            af[tt] = cvt8(lo, hi);
        }
#pragma unroll
        for (int mt = 0; mt < 4; ++mt)
            bf[mt] = *reinterpret_cast<const half8*>(
                smem + 32768 + (q4 * 64 + mt * 16 + l15) * 16);
#pragma unroll
        for (int tt = 0; tt < 4; ++tt)
#pragma unroll
            for (int mt = 0; mt < 4; ++mt)
                acc[tt][mt] = __builtin_amdgcn_mfma_f32_16x16x32_f16(
                    af[tt], bf[mt], acc[tt][mt], 0, 0, 0);
    }
    __syncthreads();   // frag reads done; wT aliases A/B

    // ======== softmax over m in registers (reduce over l15) ========
#pragma unroll
    for (int tt = 0; tt < 4; ++tt)
#pragma unroll
        for (int rg = 0; rg < 4; ++rg) {
            float mx = fmaxf(fmaxf(acc[tt][0][rg], acc[tt][1][rg]),
                             fmaxf(acc[tt][2][rg], acc[tt][3][rg]));
#pragma unroll
            for (int msk = 1; msk <= 8; msk <<= 1)
                mx = fmaxf(mx, __shfl_xor(mx, msk, 64));
            float e0 = __expf(acc[tt][0][rg] - mx);
            float e1 = __expf(acc[tt][1][rg] - mx);
            float e2 = __expf(acc[tt][2][rg] - mx);
            float e3 = __expf(acc[tt][3][rg] - mx);
            float sm = (e0 + e1) + (e2 + e3);
#pragma unroll
            for (int msk = 1; msk <= 8; msk <<= 1)
                sm += __shfl_xor(sm, msk, 64);
            float inv = 1.0f / sm;
            acc[tt][0][rg] = e0 * inv;
            acc[tt][1][rg] = e1 * inv;
            acc[tt][2][rg] = e2 * inv;
            acc[tt][3][rg] = e3 * inv;
        }
    // pack w -> wT[m][t] fp16, pitch 264
#pragma unroll
    for (int tt = 0; tt < 4; ++tt)
#pragma unroll
        for (int mt = 0; mt < 4; ++mt) {
            uint2 pk = {f2h2(acc[tt][mt][0], acc[tt][mt][1]),
                        f2h2(acc[tt][mt][2], acc[tt][mt][3])};
            *reinterpret_cast<uint2*>(
                wT + (mt * 16 + l15) * 264 + wv * 64 + tt * 16 + q4 * 4) = pk;
        }
    __syncthreads();

    // ======== segmented suffix gate scan (4 segments x 64 t) ========
    {
        const int g = tid >> 6, m_s = tid & 63;
        unsigned short* rowp = wT + m_s * 264 + g * 64;
        float pband = 1.0f;
#pragma unroll
        for (int oct = 0; oct < 8; ++oct) {
            short8 v = *reinterpret_cast<const short8*>(rowp + oct * 8);
#pragma unroll
            for (int j = 0; j < 8; ++j)
                pband *= fmaf(-ALPHA_, h2f((unsigned short)v[j]), 1.0f);
        }
        segprod[m_s * 4 + g] = pband;
        __syncthreads();
        float R = 1.0f;
#pragma unroll
        for (int gg = 1; gg < 4; ++gg)
            if (g + gg < 4) R *= segprod[m_s * 4 + g + gg];
#pragma unroll
        for (int oct = 7; oct >= 0; --oct) {
            short8 v = *reinterpret_cast<const short8*>(rowp + oct * 8);
            short8 o;
#pragma unroll
            for (int j = 7; j >= 0; --j) {
                float w = h2f((unsigned short)v[j]);
                _Float16 we = (_Float16)(ALPHA_ * w * R);
                o[j] = (short)__builtin_bit_cast(unsigned short, we);
                R *= fmaf(-ALPHA_, w, 1.0f);
            }
            *reinterpret_cast<short8*>(rowp + oct * 8) = o;
        }
    }
    __syncthreads();   // w_eff visible

    // ======== partial GEMM: pacc[m][d] += w_eff^T . H_head (fp16) ========
    f32x4 pacc[4] = {};   // wave owns m[wv*16,+16), 4 d-tiles of 16
    for (int hf = 0; hf < 2; ++hf) {
        if (hf) __syncthreads();
        // stage Hh: H fp32 [256t][32d] -> fp16 [d][t], pitch 264 (r3-verified)
        {
            const int dl = tid & 31, tg = tid >> 5;
            const float* src = H + Hrow * D_ + (size_t)(tg * 32) * D_
                               + h * 64 + hf * 32 + dl;
            unsigned short* dst = Hh + dl * 264 + tg * 32;
#pragma unroll
            for (int i = 0; i < 32; i += 2) {
                float a  = src[(size_t)i * D_];
                float bb = src[(size_t)(i + 1) * D_];
                *reinterpret_cast<unsigned int*>(dst + i) = f2h2(a, bb);
            }
        }
        __syncthreads();
#pragma unroll
        for (int ks = 0; ks < 8; ++ks) {
            half8 a = *reinterpret_cast<const half8*>(
                wT + (wv * 16 + l15) * 264 + ks * 32 + q4 * 8);
#pragma unroll
            for (int dt = 0; dt < 2; ++dt) {
                half8 bb = *reinterpret_cast<const half8*>(
                    Hh + (dt * 16 + l15) * 264 + ks * 32 + q4 * 8);
                pacc[hf * 2 + dt] = __builtin_amdgcn_mfma_f32_16x16x32_f16(
                    a, bb, pacc[hf * 2 + dt], 0, 0, 0);
            }
        }
    }

    const int chunkIdx = (b * NH_ + h) * CCH + c;
    if (tid < 64)
        chunkprod[(size_t)chunkIdx * 64 + tid] =
            (segprod[tid * 4 + 0] * segprod[tid * 4 + 1]) *
            (segprod[tid * 4 + 2] * segprod[tid * 4 + 3]);
#pragma unroll
    for (int dt = 0; dt < 4; ++dt)
#pragma unroll
        for (int rg = 0; rg < 4; ++rg)
            partial[((size_t)chunkIdx * 64 + wv * 16 + q4 * 4 + rg) * 64 + dt * 16 + l15] =
                pacc[dt][rg];
}

// ---------------------------------------------------------------------------
// Kernel 2: combine 16 chunks; grid (12, 8, 4) — mg picks 16 m-rows.
// ---------------------------------------------------------------------------
__global__ __launch_bounds__(256) void k2(const float* __restrict__ chunkprod,
                                          const float* __restrict__ partial,
                                          const float* __restrict__ s0,
                                          float* __restrict__ out) {
    const int h = blockIdx.x;
    const int b = blockIdx.y;
    const int mg = blockIdx.z;
    const int tid = threadIdx.x;
    const int m  = mg * 16 + (tid >> 4);
    const int d0 = (tid & 15) * 4;

    const size_t cpBase = (size_t)(b * NH_ + h) * CCH;
    float sfx[CCH];
    float run = 1.0f;
#pragma unroll
    for (int c = CCH - 1; c >= 0; --c) {
        sfx[c] = run;
        run *= chunkprod[(cpBase + c) * M_ + m];
    }
    const float4 v0 = *reinterpret_cast<const float4*>(
        s0 + (size_t)m * D_ + h * 64 + d0);
    float4 acc = make_float4(v0.x * run, v0.y * run, v0.z * run, v0.w * run);
#pragma unroll
    for (int c = 0; c < CCH; ++c) {
        const float sv = sfx[c];
        const float4 pp = *reinterpret_cast<const float4*>(
            partial + ((cpBase + c) * M_ + m) * 64 + d0);
        acc.x = fmaf(sv, pp.x, acc.x);
        acc.y = fmaf(sv, pp.y, acc.y);
        acc.z = fmaf(sv, pp.z, acc.z);
        acc.w = fmaf(sv, pp.w, acc.w);
    }
    *reinterpret_cast<float4*>(out + (size_t)(b * M_ + m) * D_ + h * 64 + d0) = acc;
}

// ---------------------------------------------------------------------------
extern "C" void kernel_launch(void* const* d_in, const int* in_sizes, int n_in,
                              void* d_out, int out_size, void* d_ws, size_t ws_size,
                              hipStream_t stream) {
    const float* H     = (const float*)d_in[0];
    const float* proto = (const float*)d_in[1];
    const float* W     = (const float*)d_in[2];
    const float* s0    = (const float*)d_in[3];
    float* out = (float*)d_out;

    // ws: P16 u16[589824] (1.18 MB) | chunkprod f32[98304] (0.39 MB)
    //     | partial f32[6291456] (25.2 MB)                       ~26.7 MB total
    unsigned short* P16 = (unsigned short*)d_ws;
    float* chunkprod = (float*)((unsigned char*)d_ws + 1179648);
    float* partial   = (float*)((unsigned char*)d_ws + 1572864);

    kP<<<dim3(6, NH_), 256, 0, stream>>>(proto, W, P16);
    k1<<<dim3(1536), 256, LDS_BYTES, stream>>>(H, P16, chunkprod, partial);
    k2<<<dim3(NH_, B_, 4), 256, 0, stream>>>(chunkprod, partial, s0, out);
}

// Round 10
// 234.547 us; speedup vs baseline: 1.7852x; 1.5946x over previous
//
#include <hip/hip_runtime.h>

#define B_ 8
#define T_ 4096
#define D_ 768
#define NH_ 12
#define M_ 64
#define ALPHA_ 0.1f

#define CCH 16         // chunks over T
#define CHUNK_T 256    // t per block

using half8 = __attribute__((ext_vector_type(8))) _Float16;
using short8 = __attribute__((ext_vector_type(8))) short;
using f32x4 = __attribute__((ext_vector_type(4))) float;

__device__ __forceinline__ unsigned int f2h2(float a, float b) {
    unsigned short ua = __builtin_bit_cast(unsigned short, (_Float16)a);
    unsigned short ub = __builtin_bit_cast(unsigned short, (_Float16)b);
    return (unsigned int)ua | ((unsigned int)ub << 16);
}
__device__ __forceinline__ float h2f(unsigned short u) {
    return (float)__builtin_bit_cast(_Float16, u);
}
// async global->LDS, 16 B per lane; LDS dst = wave-uniform base + lane*16
__device__ __forceinline__ void gload_lds16(const void* g, void* l) {
    __builtin_amdgcn_global_load_lds(
        (const __attribute__((address_space(1))) unsigned int*)g,
        (__attribute__((address_space(3))) unsigned int*)l, 16, 0, 0);
}

// ---------------------------------------------------------------------------
// kprep (r6-verified): heterogeneous. Blocks [0,6144): H fp32 -> fp16.
// Blocks [6144,6216): P16[h,m,e] = (1/8)*sum_i proto[m,h*64+i]*W[h*64+i,e].
// ---------------------------------------------------------------------------
__global__ __launch_bounds__(256) void kprep(const float* __restrict__ H,
                                             const float* __restrict__ proto,
                                             const float* __restrict__ W,
                                             unsigned short* __restrict__ H16,
                                             unsigned short* __restrict__ P16) {
    const int tid = threadIdx.x;
    __shared__ __align__(16) float Ws[64 * 128];
    __shared__ __align__(16) float Ks[64 * 64];

    if (blockIdx.x < 6144) {
        const int i = blockIdx.x * 256 + tid;
#pragma unroll
        for (int j = 0; j < 4; ++j) {
            const int idx = i + j * 1572864;
            const float4 v = reinterpret_cast<const float4*>(H)[idx];
            uint2 pk = {f2h2(v.x, v.y), f2h2(v.z, v.w)};
            reinterpret_cast<uint2*>(H16)[idx] = pk;
        }
        return;
    }
    const int r  = blockIdx.x - 6144;
    const int et = r % 6;
    const int h  = r / 6;

#pragma unroll
    for (int j = 0; j < 8; ++j) {
        int f = tid + j * 256;
        int i = f >> 5, c4 = f & 31;
        const float4 v = *reinterpret_cast<const float4*>(
            W + (size_t)(h * 64 + i) * D_ + et * 128 + c4 * 4);
        *reinterpret_cast<float4*>(&Ws[i * 128 + c4 * 4]) = v;
    }
#pragma unroll
    for (int j = 0; j < 4; ++j) {
        int f = tid + j * 256;
        int m = f >> 4, i4 = f & 15;
        const float4 v = *reinterpret_cast<const float4*>(
            proto + (size_t)m * D_ + h * 64 + i4 * 4);
        Ks[(i4 * 4 + 0) * 64 + m] = v.x;
        Ks[(i4 * 4 + 1) * 64 + m] = v.y;
        Ks[(i4 * 4 + 2) * 64 + m] = v.z;
        Ks[(i4 * 4 + 3) * 64 + m] = v.w;
    }
    __syncthreads();

    const int m0 = (tid >> 5) * 8;
    const int e0 = (tid & 31) * 4;
    float acc[8][4];
#pragma unroll
    for (int i = 0; i < 8; ++i)
#pragma unroll
        for (int j = 0; j < 4; ++j) acc[i][j] = 0.f;

    for (int i = 0; i < 64; ++i) {
        const float4 bb = *reinterpret_cast<const float4*>(&Ws[i * 128 + e0]);
        const float4 a0 = *reinterpret_cast<const float4*>(&Ks[i * 64 + m0]);
        const float4 a1 = *reinterpret_cast<const float4*>(&Ks[i * 64 + m0 + 4]);
        const float a[8] = {a0.x, a0.y, a0.z, a0.w, a1.x, a1.y, a1.z, a1.w};
#pragma unroll
        for (int mi = 0; mi < 8; ++mi) {
            acc[mi][0] = fmaf(a[mi], bb.x, acc[mi][0]);
            acc[mi][1] = fmaf(a[mi], bb.y, acc[mi][1]);
            acc[mi][2] = fmaf(a[mi], bb.z, acc[mi][2]);
            acc[mi][3] = fmaf(a[mi], bb.w, acc[mi][3]);
        }
    }
#pragma unroll
    for (int mi = 0; mi < 8; ++mi) {
        size_t idx = (size_t)(h * 64 + m0 + mi) * D_ + et * 128 + e0;
        uint2 pk = {f2h2(acc[mi][0] * 0.125f, acc[mi][1] * 0.125f),
                    f2h2(acc[mi][2] * 0.125f, acc[mi][3] * 0.125f)};
        *reinterpret_cast<uint2*>(P16 + idx) = pk;
    }
}

// ---------------------------------------------------------------------------
// Kernel 1 (r5-verified, byte-identical): per (chunk=256t, head, batch).
// Score GEMM stages A (H16) and B (P16) via global_load_lds w=16 with
// granule XOR-swizzle (g' = g ^ (row&7)); register softmax; segmented
// suffix scan; fp16 MFMA partial.
// grid 1536 (b = p&7 pins batch per XCD), 256 threads, dyn LDS 51712 B.
//
// LDS (bytes): [0,32768) A fp16[256t][64k] swz | [32768,40960) B[64m][64k]
//   alias: [0,33792) wT fp16[64m][264t] | [33792,50688) Hh fp16[32d][264t]
//   [50688,51712) segprod f32[64][4]
// ---------------------------------------------------------------------------
#define LDS_BYTES 51712

__global__ __launch_bounds__(256, 3) void k1(const unsigned short* __restrict__ H16,
                                             const unsigned short* __restrict__ P16,
                                             float* __restrict__ chunkprod,
                                             float* __restrict__ partial) {
    const int p = blockIdx.x;
    const int b = p & 7;
    const int s = p >> 3;
    const int h = s % 12;
    const int c = s / 12;
    const int tid = threadIdx.x;
    const int wv  = tid >> 6;
    const int lane = tid & 63;
    const int l15 = lane & 15;
    const int q4  = lane >> 4;

    extern __shared__ __align__(16) unsigned char smem[];
    unsigned short* wT = (unsigned short*)(smem);
    unsigned short* Hh = (unsigned short*)(smem + 33792);
    float* segprod = (float*)(smem + 50688);

    const size_t Hrow = (size_t)(b * T_ + c * CHUNK_T);
    const unsigned short* gA = H16 + Hrow * D_;
    const unsigned short* gB = P16 + (size_t)h * 64 * D_;

    // ======== score GEMM: 256t x 64m, K=768, fp16, DMA-staged ========
    f32x4 acc[4][4] = {};   // t = tt*16+q4*4+rg, m = mt*16+l15; wave owns t[wv*64,+64)

    for (int kt = 0; kt < 12; ++kt) {
        __syncthreads();
#pragma unroll
        for (int j = 0; j < 8; ++j) {
            int sl = j * 256 + tid;
            int rr = sl >> 3, gp = sl & 7, g = gp ^ (rr & 7);
            gload_lds16(gA + (size_t)rr * D_ + kt * 64 + g * 8, smem + sl * 16);
        }
#pragma unroll
        for (int j = 0; j < 2; ++j) {
            int sl = j * 256 + tid;
            int rr = sl >> 3, gp = sl & 7, g = gp ^ (rr & 7);
            gload_lds16(gB + (size_t)rr * D_ + kt * 64 + g * 8, smem + 32768 + sl * 16);
        }
        __syncthreads();
#pragma unroll
        for (int ks = 0; ks < 2; ++ks) {
            const int gp = ((ks * 4 + q4) ^ (l15 & 7)) * 16;
            half8 af[4], bf[4];
#pragma unroll
            for (int tt = 0; tt < 4; ++tt)
                af[tt] = *reinterpret_cast<const half8*>(
                    smem + (wv * 64 + tt * 16 + l15) * 128 + gp);
#pragma unroll
            for (int mt = 0; mt < 4; ++mt)
                bf[mt] = *reinterpret_cast<const half8*>(
                    smem + 32768 + (mt * 16 + l15) * 128 + gp);
#pragma unroll
            for (int tt = 0; tt < 4; ++tt)
#pragma unroll
                for (int mt = 0; mt < 4; ++mt)
                    acc[tt][mt] = __builtin_amdgcn_mfma_f32_16x16x32_f16(
                        af[tt], bf[mt], acc[tt][mt], 0, 0, 0);
        }
    }
    __syncthreads();   // frag reads done; wT aliases A/B

    // ======== softmax over m in registers (reduce over l15) ========
#pragma unroll
    for (int tt = 0; tt < 4; ++tt)
#pragma unroll
        for (int rg = 0; rg < 4; ++rg) {
            float mx = fmaxf(fmaxf(acc[tt][0][rg], acc[tt][1][rg]),
                             fmaxf(acc[tt][2][rg], acc[tt][3][rg]));
#pragma unroll
            for (int msk = 1; msk <= 8; msk <<= 1)
                mx = fmaxf(mx, __shfl_xor(mx, msk, 64));
            float e0 = __expf(acc[tt][0][rg] - mx);
            float e1 = __expf(acc[tt][1][rg] - mx);
            float e2 = __expf(acc[tt][2][rg] - mx);
            float e3 = __expf(acc[tt][3][rg] - mx);
            float sm = (e0 + e1) + (e2 + e3);
#pragma unroll
            for (int msk = 1; msk <= 8; msk <<= 1)
                sm += __shfl_xor(sm, msk, 64);
            float inv = 1.0f / sm;
            acc[tt][0][rg] = e0 * inv;
            acc[tt][1][rg] = e1 * inv;
            acc[tt][2][rg] = e2 * inv;
            acc[tt][3][rg] = e3 * inv;
        }
    // pack w -> wT[m][t] fp16, pitch 264
#pragma unroll
    for (int tt = 0; tt < 4; ++tt)
#pragma unroll
        for (int mt = 0; mt < 4; ++mt) {
            uint2 pk = {f2h2(acc[tt][mt][0], acc[tt][mt][1]),
                        f2h2(acc[tt][mt][2], acc[tt][mt][3])};
            *reinterpret_cast<uint2*>(
                wT + (mt * 16 + l15) * 264 + wv * 64 + tt * 16 + q4 * 4) = pk;
        }
    __syncthreads();

    // ======== segmented suffix gate scan (4 segments x 64 t) ========
    {
        const int g = tid >> 6, m_s = tid & 63;
        unsigned short* rowp = wT + m_s * 264 + g * 64;
        float pband = 1.0f;
#pragma unroll
        for (int oct = 0; oct < 8; ++oct) {
            short8 v = *reinterpret_cast<const short8*>(rowp + oct * 8);
#pragma unroll
            for (int j = 0; j < 8; ++j)
                pband *= fmaf(-ALPHA_, h2f((unsigned short)v[j]), 1.0f);
        }
        segprod[m_s * 4 + g] = pband;
        __syncthreads();
        float R = 1.0f;
#pragma unroll
        for (int gg = 1; gg < 4; ++gg)
            if (g + gg < 4) R *= segprod[m_s * 4 + g + gg];
#pragma unroll
        for (int oct = 7; oct >= 0; --oct) {
            short8 v = *reinterpret_cast<const short8*>(rowp + oct * 8);
            short8 o;
#pragma unroll
            for (int j = 7; j >= 0; --j) {
                float w = h2f((unsigned short)v[j]);
                _Float16 we = (_Float16)(ALPHA_ * w * R);
                o[j] = (short)__builtin_bit_cast(unsigned short, we);
                R *= fmaf(-ALPHA_, w, 1.0f);
            }
            *reinterpret_cast<short8*>(rowp + oct * 8) = o;
        }
    }
    __syncthreads();   // w_eff visible

    // ======== partial GEMM: pacc[m][d] += w_eff^T . H_head (fp16) ========
    f32x4 pacc[4] = {};   // wave owns m[wv*16,+16), 4 d-tiles of 16
    for (int hf = 0; hf < 2; ++hf) {
        if (hf) __syncthreads();
        // stage Hh: H16[256 t][32 d] -> [d][t], pitch 264
        {
            const int dp = tid & 15, tg = tid >> 4;
            const unsigned short* src = H16 + (Hrow + tg * 16) * D_
                                        + h * 64 + hf * 32 + 2 * dp;
            unsigned short* dst0 = Hh + (2 * dp) * 264 + tg * 16;
            unsigned short* dst1 = Hh + (2 * dp + 1) * 264 + tg * 16;
#pragma unroll
            for (int i = 0; i < 16; ++i) {
                unsigned int v = *reinterpret_cast<const unsigned int*>(src + (size_t)i * D_);
                dst0[i] = (unsigned short)(v & 0xffffu);
                dst1[i] = (unsigned short)(v >> 16);
            }
        }
        __syncthreads();
#pragma unroll
        for (int ks = 0; ks < 8; ++ks) {
            half8 a = *reinterpret_cast<const half8*>(
                wT + (wv * 16 + l15) * 264 + ks * 32 + q4 * 8);
#pragma unroll
            for (int dt = 0; dt < 2; ++dt) {
                half8 bb = *reinterpret_cast<const half8*>(
                    Hh + (dt * 16 + l15) * 264 + ks * 32 + q4 * 8);
                pacc[hf * 2 + dt] = __builtin_amdgcn_mfma_f32_16x16x32_f16(
                    a, bb, pacc[hf * 2 + dt], 0, 0, 0);
            }
        }
    }

    const int chunkIdx = (b * NH_ + h) * CCH + c;
    if (tid < 64)
        chunkprod[(size_t)chunkIdx * 64 + tid] =
            (segprod[tid * 4 + 0] * segprod[tid * 4 + 1]) *
            (segprod[tid * 4 + 2] * segprod[tid * 4 + 3]);
#pragma unroll
    for (int dt = 0; dt < 4; ++dt)
#pragma unroll
        for (int rg = 0; rg < 4; ++rg)
            partial[((size_t)chunkIdx * 64 + wv * 16 + q4 * 4 + rg) * 64 + dt * 16 + l15] =
                pacc[dt][rg];
}

// ---------------------------------------------------------------------------
// Kernel 2 (r5-verified): combine 16 chunks; grid (12, 8, 4).
// ---------------------------------------------------------------------------
__global__ __launch_bounds__(256) void k2(const float* __restrict__ chunkprod,
                                          const float* __restrict__ partial,
                                          const float* __restrict__ s0,
                                          float* __restrict__ out) {
    const int h = blockIdx.x;
    const int b = blockIdx.y;
    const int mg = blockIdx.z;
    const int tid = threadIdx.x;
    const int m  = mg * 16 + (tid >> 4);
    const int d0 = (tid & 15) * 4;

    const size_t cpBase = (size_t)(b * NH_ + h) * CCH;
    float sfx[CCH];
    float run = 1.0f;
#pragma unroll
    for (int c = CCH - 1; c >= 0; --c) {
        sfx[c] = run;
        run *= chunkprod[(cpBase + c) * M_ + m];
    }
    const float4 v0 = *reinterpret_cast<const float4*>(
        s0 + (size_t)m * D_ + h * 64 + d0);
    float4 acc = make_float4(v0.x * run, v0.y * run, v0.z * run, v0.w * run);
#pragma unroll
    for (int c = 0; c < CCH; ++c) {
        const float sv = sfx[c];
        const float4 pp = *reinterpret_cast<const float4*>(
            partial + ((cpBase + c) * M_ + m) * 64 + d0);
        acc.x = fmaf(sv, pp.x, acc.x);
        acc.y = fmaf(sv, pp.y, acc.y);
        acc.z = fmaf(sv, pp.z, acc.z);
        acc.w = fmaf(sv, pp.w, acc.w);
    }
    *reinterpret_cast<float4*>(out + (size_t)(b * M_ + m) * D_ + h * 64 + d0) = acc;
}

// ---------------------------------------------------------------------------
extern "C" void kernel_launch(void* const* d_in, const int* in_sizes, int n_in,
                              void* d_out, int out_size, void* d_ws, size_t ws_size,
                              hipStream_t stream) {
    const float* H     = (const float*)d_in[0];
    const float* proto = (const float*)d_in[1];
    const float* W     = (const float*)d_in[2];
    const float* s0    = (const float*)d_in[3];
    float* out = (float*)d_out;

    // ws: H16 u16[25165824] (50.3 MB) | P16 u16[589824] (1.18 MB)
    //     | chunkprod f32[98304] | partial f32[6291456] (25.2 MB)   ~77 MB
    unsigned short* H16 = (unsigned short*)d_ws;
    unsigned short* P16 = (unsigned short*)((unsigned char*)d_ws + 50331648);
    float* chunkprod = (float*)((unsigned char*)d_ws + 51511296);
    float* partial   = (float*)((unsigned char*)d_ws + 51904512);

    kprep<<<dim3(6216), 256, 0, stream>>>(H, proto, W, H16, P16);
    k1<<<dim3(1536), 256, LDS_BYTES, stream>>>(H16, P16, chunkprod, partial);
    k2<<<dim3(NH_, B_, 4), 256, 0, stream>>>(chunkprod, partial, s0, out);
}